// Round 9
// baseline (73.742 us; speedup 1.0000x reference)
//
#include <hip/hip_runtime.h>
#include <math.h>
#include <stdint.h>

// Problem: ProcessFeatures_83296595738632
// corr[bs,bg,i] = sum_{h,j,k} sat[bs,h,(i+j)%64,k] * grd[bg,h,j,15-k]
// orien = argmax_i corr (first-max); dot with cyclic shift orien, /||sat||
// distance[bg,bs] = 2-2*dot[bs,bg]; out: sat | grd | distance | orien(float)
//
// R9: R8 + forced software pipeline:
//  - per-jj: [issue A ds_reads + B vmem loads for jj+1] sched_barrier
//            [16 MFMAs on jj's registered buffers] sched_barrier
//    -> compiler emits counted lgkmcnt(8)/vmcnt(8), loads stay in flight
//  - 4 accumulators (one per q) -> short MFMA dep chains
//  - s_setprio around MFMA cluster
//  - passthrough copies folded into pf_pack_b

#define BS   96
#define H    4
#define W    64
#define C    16
#define BG   96
#define HWC  (H*W*C)                  // 4096

#define SAT_ELEMS (BS*H*W*C)          // 393216
#define OUT_DIST  (2*SAT_ELEMS)       // 786432
#define OUT_ORIEN (OUT_DIST + BS*BG)  // 795648

#define WS_NEEDED ((size_t)2 * SAT_ELEMS * 2)   // 1.5 MB

typedef __attribute__((ext_vector_type(4)))  short short4v;
typedef __attribute__((ext_vector_type(8)))  short short8v;
typedef __attribute__((ext_vector_type(16))) float f32x16;

__device__ __forceinline__ void bsplit(float x, unsigned short& hi, unsigned short& lo) {
    unsigned int u = __float_as_uint(x);
    unsigned int r = (u + 0x7FFFu + ((u >> 16) & 1u)) >> 16;   // RNE to bf16
    hi = (unsigned short)r;
    float hf = __uint_as_float(r << 16);
    float l = x - hf;
    unsigned int ul = __float_as_uint(l);
    unsigned int rl = (ul + 0x7FFFu + ((ul >> 16) & 1u)) >> 16;
    lo = (unsigned short)rl;
}

// ---------------- prologue: pack B fragments + passthrough copies ----------------
// Bpk fragment (j,bgq,q,pl,lane,e) = plane pl of grdR[j][bgq*32+(lane&31)][q*16+(lane>>5)*8+e]
// grdR[j][bg][hk] = grd[bg][hk>>4][j][15-(hk&15)];  hk in [16q,16q+16) -> h = q.
__global__ __launch_bounds__(512)
void pf_pack_b(const float* __restrict__ sat, const float* __restrict__ grd,
               unsigned short* __restrict__ Bpk, float* __restrict__ out)
{
    int t = blockIdx.x * 512 + threadIdx.x;    // < 49152 = 64*3*4*64
    int lane = t & 63;
    int q    = (t >> 6) & 3;
    int bgq  = (t >> 8) % 3;
    int j    = t / 768;
    int l31 = lane & 31, l5 = lane >> 5;
    int bg = bgq * 32 + l31;

    const float* row = grd + ((size_t)(bg * 4 + q) * 64 + j) * 16 + (8 - 8 * l5);
    float tmp[8];
    *(float4*)&tmp[0] = *(const float4*)(row);
    *(float4*)&tmp[4] = *(const float4*)(row + 4);

    short8v hv, lv;
    #pragma unroll
    for (int e = 0; e < 8; ++e) {
        unsigned short hi, lo;
        bsplit(tmp[7 - e], hi, lo);          // value[e] = row[7-e]  (k = 15-8*l5-e)
        hv[e] = (short)hi; lv[e] = (short)lo;
    }
    size_t base = ((size_t)((j * 3 + bgq) * 4 + q) * 2) << 9;
    *(short8v*)&Bpk[base + lane * 8]       = hv;   // plane 0 (hi)
    *(short8v*)&Bpk[base + 512 + lane * 8] = lv;   // plane 1 (lo)

    // passthrough copies: out[0..] = sat, out[SAT..] = grd (float4, grid-stride)
    const float4* s4 = (const float4*)sat;
    const float4* g4 = (const float4*)grd;
    float4* o4 = (float4*)out;
    #pragma unroll
    for (int idx = t; idx < 2 * SAT_ELEMS / 4; idx += 49152) {
        o4[idx] = (idx < SAT_ELEMS / 4) ? s4[idx] : g4[idx - SAT_ELEMS / 4];
    }
}

// ---------------- fused: corr MFMA + argmax + dot + distance ----------------
#define MFMA(a, b, c) __builtin_amdgcn_mfma_f32_32x32x16_bf16((a), (b), (c), 0, 0, 0)

__global__ __launch_bounds__(512, 2)
void pf_fused(const float* __restrict__ sat, const float* __restrict__ grd,
              const unsigned short* __restrict__ Bpk, float* __restrict__ out)
{
    __shared__ unsigned short sHi[4096], sLo[4096];   // satM planes, swizzled (16 KB)
    __shared__ float corrPart[4][64][33];             // 33.8 KB
    __shared__ float redW[8];
    __shared__ int   orienL[32];

    const int bs  = blockIdx.y;
    const int bgq = blockIdx.x;
    const int bg0 = bgq * 32;
    const int tid = threadIdx.x;
    const int wv  = tid >> 6, lane = tid & 63;
    const int l31 = lane & 31, l5 = lane >> 5;
    const int mh  = wv & 1, kq = wv >> 1;   // M-half, K-quarter (16 j each)

    // ---- stage satM (swizzled bf16 hi/lo) + norm partial ----
    // satM[w][hk] = sat[bs][hk>>4][w][hk&15]; chunk cc=hk>>3 at slot cc^(w&7)
    {
        const float4* satB = (const float4*)(sat + (size_t)bs * HWC);
        float np = 0.f;
        #pragma unroll
        for (int t = tid; t < 1024; t += 512) {
            float4 v = satB[t];
            int e = 4 * t;
            int h = e >> 10, w = (e >> 4) & 63, k = e & 15;
            int cc = (h * 16 + k) >> 3;
            int dst = w * 64 + ((cc ^ (w & 7)) * 8) + (k & 7);
            short4v hvv, lvv;
            unsigned short hi, lo;
            bsplit(v.x, hi, lo); hvv[0] = hi; lvv[0] = lo;
            bsplit(v.y, hi, lo); hvv[1] = hi; lvv[1] = lo;
            bsplit(v.z, hi, lo); hvv[2] = hi; lvv[2] = lo;
            bsplit(v.w, hi, lo); hvv[3] = hi; lvv[3] = lo;
            *(short4v*)&sHi[dst] = hvv;
            *(short4v*)&sLo[dst] = lvv;
            np = fmaf(v.x, v.x, fmaf(v.y, v.y, fmaf(v.z, v.z, fmaf(v.w, v.w, np))));
        }
        #pragma unroll
        for (int off = 32; off; off >>= 1) np += __shfl_xor(np, off);
        if (lane == 0) redW[wv] = np;
    }
    __syncthreads();

    // ---- corr GEMM: bf16x4, wave = (mh, kq), tile 32x32, K-slice 1024 ----
    f32x16 acc0, acc1, acc2, acc3;
    #pragma unroll
    for (int i = 0; i < 16; ++i) { acc0[i] = 0.f; acc1[i] = 0.f; acc2[i] = 0.f; acc3[i] = 0.f; }

    const int rbase = mh * 32 + l31 + kq * 16;
    const int laneB = lane * 8;
    #define BIDX(jA, f) ((((size_t)((jA) * 3 + bgq) * 8 + (f)) << 9) + laneB)

    short8v a0[8], a1[8], b0[8], b1[8];

    #define LOAD_A(arr, jj_) { \
        const int r_ = (rbase + (jj_)) & 63; \
        const int rsw_ = r_ & 7; \
        const int arow_ = r_ * 64; \
        _Pragma("unroll") \
        for (int q_ = 0; q_ < 4; ++q_) { \
            const int aoff_ = arow_ + ((((q_ * 2 + l5)) ^ rsw_) * 8); \
            arr[q_ * 2]     = *(const short8v*)&sHi[aoff_]; \
            arr[q_ * 2 + 1] = *(const short8v*)&sLo[aoff_]; \
        } }

    #define LOAD_B(arr, jj_) { \
        const int jA_ = kq * 16 + (jj_); \
        _Pragma("unroll") \
        for (int f_ = 0; f_ < 8; ++f_) \
            arr[f_] = *(const short8v*)&Bpk[BIDX(jA_, f_)]; }

    #define DO_MFMA(aarr, barr) { \
        __builtin_amdgcn_s_setprio(1); \
        acc0 = MFMA(aarr[0], barr[0], acc0); \
        acc0 = MFMA(aarr[0], barr[1], acc0); \
        acc1 = MFMA(aarr[2], barr[2], acc1); \
        acc1 = MFMA(aarr[2], barr[3], acc1); \
        acc2 = MFMA(aarr[4], barr[4], acc2); \
        acc2 = MFMA(aarr[4], barr[5], acc2); \
        acc3 = MFMA(aarr[6], barr[6], acc3); \
        acc3 = MFMA(aarr[6], barr[7], acc3); \
        acc0 = MFMA(aarr[1], barr[0], acc0); \
        acc0 = MFMA(aarr[1], barr[1], acc0); \
        acc1 = MFMA(aarr[3], barr[2], acc1); \
        acc1 = MFMA(aarr[3], barr[3], acc1); \
        acc2 = MFMA(aarr[5], barr[4], acc2); \
        acc2 = MFMA(aarr[5], barr[5], acc2); \
        acc3 = MFMA(aarr[7], barr[6], acc3); \
        acc3 = MFMA(aarr[7], barr[7], acc3); \
        __builtin_amdgcn_s_setprio(0); }

    LOAD_A(a0, 0); LOAD_B(b0, 0);
    #pragma unroll
    for (int jj = 0; jj < 16; jj += 2) {
        if (jj + 1 < 16) { LOAD_A(a1, jj + 1); LOAD_B(b1, jj + 1); }
        __builtin_amdgcn_sched_barrier(0);
        DO_MFMA(a0, b0);
        __builtin_amdgcn_sched_barrier(0);
        if (jj + 2 < 16) { LOAD_A(a0, jj + 2); LOAD_B(b0, jj + 2); }
        __builtin_amdgcn_sched_barrier(0);
        DO_MFMA(a1, b1);
        __builtin_amdgcn_sched_barrier(0);
    }
    #undef BIDX
    #undef LOAD_A
    #undef LOAD_B
    #undef DO_MFMA

    // ---- C/D -> corrPart (row = (reg&3)+8*(reg>>2)+4*l5 + mh*32, col = l31) ----
    #pragma unroll
    for (int reg = 0; reg < 16; ++reg) {
        int row = mh * 32 + (reg & 3) + 8 * (reg >> 2) + 4 * l5;
        corrPart[kq][row][l31] = (acc0[reg] + acc1[reg]) + (acc2[reg] + acc3[reg]);
    }
    __syncthreads();

    // ---- argmax per bg (first-max tie-break): wave wv -> bgc = wv*4..+3 ----
    #pragma unroll
    for (int u = 0; u < 4; ++u) {
        const int bgc = wv * 4 + u;
        float v = (corrPart[0][lane][bgc] + corrPart[1][lane][bgc])
                + (corrPart[2][lane][bgc] + corrPart[3][lane][bgc]);
        int idx = lane;
        #pragma unroll
        for (int off = 32; off; off >>= 1) {
            float ov = __shfl_xor(v, off);
            int   oi = __shfl_xor(idx, off);
            if (ov > v || (ov == v && oi < idx)) { v = ov; idx = oi; }
        }
        if (lane == 0) {
            orienL[bgc] = idx;
            out[OUT_ORIEN + bs * BG + bg0 + bgc] = (float)idx;
        }
    }
    __syncthreads();

    const float nrm = sqrtf(((redW[0] + redW[1]) + (redW[2] + redW[3]))
                          + ((redW[4] + redW[5]) + (redW[6] + redW[7])) + 1e-8f);

    // ---- fp32 dot + distance: wave wv -> bgc = wv*4..+3, lane = j ----
    #pragma unroll
    for (int u = 0; u < 4; ++u) {
        const int bgc = wv * 4 + u;
        const int bg = bg0 + bgc;
        const int r = (lane + orienL[bgc]) & 63;
        float s = 0.f;
        #pragma unroll
        for (int h = 0; h < 4; ++h) {
            const float4* sp = (const float4*)&sat[(((size_t)bs * 4 + h) * 64 + r) * 16];
            const float4* gp = (const float4*)&grd[(((size_t)bg * 4 + h) * 64 + lane) * 16];
            #pragma unroll
            for (int c4 = 0; c4 < 4; ++c4) {
                float4 sv = sp[c4];
                float4 gv = gp[c4];
                s = fmaf(sv.x, gv.x, fmaf(sv.y, gv.y, fmaf(sv.z, gv.z, fmaf(sv.w, gv.w, s))));
            }
        }
        #pragma unroll
        for (int off = 32; off; off >>= 1) s += __shfl_xor(s, off);
        if (lane == 0)
            out[OUT_DIST + (size_t)bg * BS + bs] = 2.f - 2.f * (s / nrm);
    }
}

// ---------------- fallback (R3, verified): used only if ws too small ----------------
__device__ __forceinline__ int satIdxFB(int hw, int c4) {
    return hw * 16 + 4 * ((c4 + (hw >> 1)) & 3);
}
__device__ __forceinline__ float rot_add(int baddr, float p) {
    return __int_as_float(__builtin_amdgcn_ds_bpermute(baddr, __float_as_int(p)));
}
__device__ __forceinline__ float dot_rev(const float4 s0, const float4 s1,
                                         const float4 s2, const float4 s3,
                                         const float* __restrict__ g) {
    float p0 = fmaf(s0.x, g[15], fmaf(s0.y, g[14], fmaf(s0.z, g[13], s0.w * g[12])));
    float p1 = fmaf(s1.x, g[11], fmaf(s1.y, g[10], fmaf(s1.z, g[ 9], s1.w * g[ 8])));
    float p2 = fmaf(s2.x, g[ 7], fmaf(s2.y, g[ 6], fmaf(s2.z, g[ 5], s2.w * g[ 4])));
    float p3 = fmaf(s3.x, g[ 3], fmaf(s3.y, g[ 2], fmaf(s3.z, g[ 1], s3.w * g[ 0])));
    return (p0 + p1) + (p2 + p3);
}
#define NB 8
__global__ __launch_bounds__(256)
void pf_fused_fb(const float* __restrict__ sat, const float* __restrict__ grd,
                 float* __restrict__ out)
{
    __shared__ float satL[H * W * C];
    __shared__ float partL[NB * 4 * W];
    __shared__ float sumL[4];
    __shared__ float dotP[NB * 4];
    __shared__ int   orienL[NB];
    const int bs = blockIdx.y, bg0 = blockIdx.x * NB;
    const int tid = threadIdx.x, wv = tid >> 6, lane = tid & 63;
    const float4* sp = (const float4*)(sat + (((size_t)bs * H + wv) * W + lane) * C);
    const float4 s0 = sp[0], s1 = sp[1], s2 = sp[2], s3 = sp[3];
    { const int hw = wv * W + lane;
      *(float4*)&satL[satIdxFB(hw,0)] = s0; *(float4*)&satL[satIdxFB(hw,1)] = s1;
      *(float4*)&satL[satIdxFB(hw,2)] = s2; *(float4*)&satL[satIdxFB(hw,3)] = s3; }
    { float a = fmaf(s0.x,s0.x,fmaf(s0.y,s0.y,fmaf(s0.z,s0.z,s0.w*s0.w)));
      float b = fmaf(s1.x,s1.x,fmaf(s1.y,s1.y,fmaf(s1.z,s1.z,s1.w*s1.w)));
      float c = fmaf(s2.x,s2.x,fmaf(s2.y,s2.y,fmaf(s2.z,s2.z,s2.w*s2.w)));
      float d = fmaf(s3.x,s3.x,fmaf(s3.y,s3.y,fmaf(s3.z,s3.z,s3.w*s3.w)));
      float s = (a+b)+(c+d);
      #pragma unroll
      for (int off = 32; off; off >>= 1) s += __shfl_xor(s, off);
      if (lane == 0) sumL[wv] = s; }
    const float* gpB = grd + (size_t)(bg0 * H + wv) * W * C;
    #pragma unroll
    for (int bp = 0; bp < NB/2; ++bp) {
        const float* gA = gpB + (2*bp) * HWC;
        const float* gB2 = gpB + (2*bp+1) * HWC;
        float accA = 0.f, accB = 0.f;
        int baddr = lane << 2;
        #pragma unroll 2
        for (int j = 0; j < W; ++j) {
            float pA = dot_rev(s0,s1,s2,s3, gA + j*C);
            float pB = dot_rev(s0,s1,s2,s3, gB2 + j*C);
            accA += rot_add(baddr, pA); accB += rot_add(baddr, pB);
            baddr = (baddr + 4) & 255;
        }
        partL[((2*bp)*4 + wv)*W + lane] = accA;
        partL[((2*bp+1)*4 + wv)*W + lane] = accB;
    }
    __syncthreads();
    for (int b = wv; b < NB; b += 4) {
        float v = (partL[(b*4+0)*W+lane] + partL[(b*4+1)*W+lane])
                + (partL[(b*4+2)*W+lane] + partL[(b*4+3)*W+lane]);
        int idx = lane;
        #pragma unroll
        for (int off = 32; off; off >>= 1) {
            float ov = __shfl_xor(v, off); int oi = __shfl_xor(idx, off);
            if (ov > v || (ov == v && oi < idx)) { v = ov; idx = oi; }
        }
        if (lane == 0) { orienL[b] = idx; out[OUT_ORIEN + bs*BG + (bg0+b)] = (float)idx; }
    }
    __syncthreads();
    const float nrm = sqrtf(sumL[0]+sumL[1]+sumL[2]+sumL[3] + 1e-8f);
    { float dp[NB];
      #pragma unroll
      for (int b = 0; b < NB; ++b) {
          const int row = (lane + orienL[b]) & 63;
          const float* gRow = grd + (((size_t)(bg0+b)*H + wv)*W + lane)*C;
          float s = 0.f;
          #pragma unroll
          for (int c4 = 0; c4 < 4; ++c4) {
              float4 sv = *(const float4*)&satL[satIdxFB(wv*W+row, c4)];
              float4 gv = *(const float4*)(gRow + 4*c4);
              s = fmaf(sv.x,gv.x, fmaf(sv.y,gv.y, fmaf(sv.z,gv.z, fmaf(sv.w,gv.w, s))));
          }
          dp[b] = s;
      }
      #pragma unroll
      for (int b = 0; b < NB; ++b) {
          float s = dp[b];
          #pragma unroll
          for (int off = 32; off; off >>= 1) s += __shfl_xor(s, off);
          if (lane == 0) dotP[b*4 + wv] = s;
      } }
    __syncthreads();
    if (tid < NB) {
        float d = ((dotP[tid*4+0]+dotP[tid*4+1])+(dotP[tid*4+2]+dotP[tid*4+3])) / nrm;
        out[OUT_DIST + (size_t)(bg0+tid)*BS + bs] = 2.f - 2.f*d;
    }
}

extern "C" void kernel_launch(void* const* d_in, const int* in_sizes, int n_in,
                              void* d_out, int out_size, void* d_ws, size_t ws_size,
                              hipStream_t stream) {
    const float* sat = (const float*)d_in[0];
    const float* grd = (const float*)d_in[1];
    float* out = (float*)d_out;

    if (ws_size < WS_NEEDED) {
        hipMemcpyAsync(out,             sat, (size_t)SAT_ELEMS * sizeof(float),
                       hipMemcpyDeviceToDevice, stream);
        hipMemcpyAsync(out + SAT_ELEMS, grd, (size_t)SAT_ELEMS * sizeof(float),
                       hipMemcpyDeviceToDevice, stream);
        dim3 grid(BG / NB, BS);
        pf_fused_fb<<<grid, 256, 0, stream>>>(sat, grd, out);
        return;
    }

    unsigned short* Bpk = (unsigned short*)d_ws;
    pf_pack_b<<<96, 512, 0, stream>>>(sat, grd, Bpk, out);
    pf_fused<<<dim3(3, BS), 512, 0, stream>>>(sat, grd, Bpk, out);
}

// Round 10
// 71.258 us; speedup vs baseline: 1.0349x; 1.0349x over previous
//
#include <hip/hip_runtime.h>
#include <math.h>
#include <stdint.h>

// Problem: ProcessFeatures_83296595738632
// corr[bs,bg,i] = sum_{h,j,k} sat[bs,h,(i+j)%64,k] * grd[bg,h,j,15-k]
// orien = argmax_i corr (first-max); dot with cyclic shift orien, /||sat||
// distance[bg,bs] = 2-2*dot[bs,bg]; out: sat | grd | distance | orien(float)
//
// R10: TLP restructure. mfma 16x16x32, ONE 16x16 tile per wave (acc = f32x4),
// tiny VGPR footprint, launch_bounds(512,4) -> 2-3 blocks/CU co-resident
// (4-6 waves/SIMD) to hide LDS/L2 latency. No sched fences. B pre-packed in
// 16x16 fragment order (1KB contiguous per fragment).

#define BS   96
#define H    4
#define W    64
#define C    16
#define BG   96
#define HWC  (H*W*C)                  // 4096

#define SAT_ELEMS (BS*H*W*C)          // 393216
#define OUT_DIST  (2*SAT_ELEMS)       // 786432
#define OUT_ORIEN (OUT_DIST + BS*BG)  // 795648

#define WS_NEEDED ((size_t)2 * SAT_ELEMS * 2)   // 1.5 MB

typedef __attribute__((ext_vector_type(4)))  short short4v;
typedef __attribute__((ext_vector_type(8)))  short short8v;
typedef __attribute__((ext_vector_type(4)))  float f32x4;

__device__ __forceinline__ void bsplit(float x, unsigned short& hi, unsigned short& lo) {
    unsigned int u = __float_as_uint(x);
    unsigned int r = (u + 0x7FFFu + ((u >> 16) & 1u)) >> 16;   // RNE to bf16
    hi = (unsigned short)r;
    float hf = __uint_as_float(r << 16);
    float l = x - hf;
    unsigned int ul = __float_as_uint(l);
    unsigned int rl = (ul + 0x7FFFu + ((ul >> 16) & 1u)) >> 16;
    lo = (unsigned short)rl;
}

// ---------------- prologue: pack B fragments (16x16x32 layout) + passthrough ----
// Fragment (j,kh,nt6,pl): lane l, elem e ->
//   B[k = (l>>4)*8+e][col = l&15]  of the (j,kh) K-slice, col group nt6 (16 bg)
//   = grdR[j][nt6*16 + (l&15)][kh*32 + (l>>4)*8 + e]
//   grdR[j][bg][hk] = grd[bg][hk>>4][j][15-(hk&15)]
__global__ __launch_bounds__(512)
void pf_pack_b(const float* __restrict__ sat, const float* __restrict__ grd,
               unsigned short* __restrict__ Bpk, float* __restrict__ out)
{
    int t = blockIdx.x * 512 + threadIdx.x;    // < 49152 = 64j * 2kh * 6nt * 64lane
    int lane = t & 63;
    int f    = t >> 6;            // fragment id: ((j*2+kh)*6 + nt6)
    int nt6  = f % 6;
    int g    = f / 6;
    int kh   = g & 1;
    int j    = g >> 1;

    int col = nt6 * 16 + (lane & 15);
    int u   = lane >> 4;
    int h   = kh * 2 + (u >> 1);
    int k0  = (u & 1) * 8;        // hk = kh*32 + u*8 -> within-h offset k0

    const float* row = grd + ((size_t)(col * 4 + h) * 64 + j) * 16 + (8 - k0);
    float tmp[8];
    *(float4*)&tmp[0] = *(const float4*)(row);
    *(float4*)&tmp[4] = *(const float4*)(row + 4);

    short8v hv, lv;
    #pragma unroll
    for (int e = 0; e < 8; ++e) {
        unsigned short hi, lo;
        bsplit(tmp[7 - e], hi, lo);          // value[e] = grd[...][15-k0-e]
        hv[e] = (short)hi; lv[e] = (short)lo;
    }
    size_t base = (size_t)f << 10;           // 1024 ushorts per fragment pair
    *(short8v*)&Bpk[base + lane * 8]       = hv;   // plane 0 (hi)
    *(short8v*)&Bpk[base + 512 + lane * 8] = lv;   // plane 1 (lo)

    // passthrough copies: out[0..] = sat, out[SAT..] = grd
    const float4* s4 = (const float4*)sat;
    const float4* g4 = (const float4*)grd;
    float4* o4 = (float4*)out;
    #pragma unroll
    for (int idx = t; idx < 2 * SAT_ELEMS / 4; idx += 49152) {
        o4[idx] = (idx < SAT_ELEMS / 4) ? s4[idx] : g4[idx - SAT_ELEMS / 4];
    }
}

// ---------------- fused: corr MFMA + argmax + dot + distance ----------------
#define MFMA16(a, b, c) __builtin_amdgcn_mfma_f32_16x16x32_bf16((a), (b), (c), 0, 0, 0)

__global__ __launch_bounds__(512, 4)
void pf_fused(const float* __restrict__ sat, const float* __restrict__ grd,
              const unsigned short* __restrict__ Bpk, float* __restrict__ out)
{
    __shared__ unsigned short sHi[4096], sLo[4096];   // satM planes, swizzled (16 KB)
    __shared__ float corrPart[64][33];                // 8.4 KB
    __shared__ float redW[8];
    __shared__ int   orienL[32];

    const int bs  = blockIdx.y;
    const int bgq = blockIdx.x;
    const int bg0 = bgq * 32;
    const int tid = threadIdx.x;
    const int wv  = tid >> 6, lane = tid & 63;
    const int mtile = wv >> 1, ntile = wv & 1;
    const int nt6 = bgq * 2 + ntile;
    const int u   = lane >> 4;

    // ---- stage satM (swizzled bf16 hi/lo) + norm partial ----
    // satM[w][hk] = sat[bs][hk>>4][w][hk&15]; chunk cc=hk>>3 at slot cc^(w&7)
    {
        const float4* satB = (const float4*)(sat + (size_t)bs * HWC);
        float np = 0.f;
        #pragma unroll
        for (int t = tid; t < 1024; t += 512) {
            float4 v = satB[t];
            int e = 4 * t;
            int h = e >> 10, w = (e >> 4) & 63, k = e & 15;
            int cc = (h * 16 + k) >> 3;
            int dst = w * 64 + ((cc ^ (w & 7)) * 8) + (k & 7);
            short4v hvv, lvv;
            unsigned short hi, lo;
            bsplit(v.x, hi, lo); hvv[0] = hi; lvv[0] = lo;
            bsplit(v.y, hi, lo); hvv[1] = hi; lvv[1] = lo;
            bsplit(v.z, hi, lo); hvv[2] = hi; lvv[2] = lo;
            bsplit(v.w, hi, lo); hvv[3] = hi; lvv[3] = lo;
            *(short4v*)&sHi[dst] = hvv;
            *(short4v*)&sLo[dst] = lvv;
            np = fmaf(v.x, v.x, fmaf(v.y, v.y, fmaf(v.z, v.z, fmaf(v.w, v.w, np))));
        }
        #pragma unroll
        for (int off = 32; off; off >>= 1) np += __shfl_xor(np, off);
        if (lane == 0) redW[wv] = np;
    }
    __syncthreads();

    // ---- corr GEMM: bf16x4, one 16x16 tile per wave, K = 64j x 2kh steps ----
    f32x4 acc = {0.f, 0.f, 0.f, 0.f};

    const int mbase = mtile * 16 + (lane & 15);
    const int laneB = lane * 8;
    const unsigned short* __restrict__ bbase = Bpk + ((size_t)nt6 << 10) + laneB;

    #pragma unroll 4
    for (int j = 0; j < 64; ++j) {
        const int r = (mbase + j) & 63;
        const int arow = r << 6;
        const int rsw = r & 7;
        const unsigned short* bj = bbase + ((size_t)(j * 2) * 6 << 10);
        #pragma unroll
        for (int kh = 0; kh < 2; ++kh) {
            const int cc = kh * 4 + u;
            const int aoff = arow + (((cc ^ rsw)) << 3);
            short8v ah = *(const short8v*)&sHi[aoff];
            short8v al = *(const short8v*)&sLo[aoff];
            const unsigned short* bp = bj + ((size_t)(kh * 6) << 10);
            short8v bh = *(const short8v*)bp;
            short8v bl = *(const short8v*)(bp + 512);
            acc = MFMA16(ah, bh, acc);
            acc = MFMA16(ah, bl, acc);
            acc = MFMA16(al, bh, acc);
            acc = MFMA16(al, bl, acc);
        }
    }

    // ---- C/D -> corrPart: col = lane&15 (local), row = (lane>>4)*4 + reg ----
    {
        const int gcol = ntile * 16 + (lane & 15);
        const int rrow = mtile * 16 + u * 4;
        #pragma unroll
        for (int reg = 0; reg < 4; ++reg)
            corrPart[rrow + reg][gcol] = acc[reg];
    }
    __syncthreads();

    // ---- argmax per bg (first-max tie-break): wave wv -> bgc = wv*4..+3 ----
    #pragma unroll
    for (int t = 0; t < 4; ++t) {
        const int bgc = wv * 4 + t;
        float v = corrPart[lane][bgc];
        int idx = lane;
        #pragma unroll
        for (int off = 32; off; off >>= 1) {
            float ov = __shfl_xor(v, off);
            int   oi = __shfl_xor(idx, off);
            if (ov > v || (ov == v && oi < idx)) { v = ov; idx = oi; }
        }
        if (lane == 0) {
            orienL[bgc] = idx;
            out[OUT_ORIEN + bs * BG + bg0 + bgc] = (float)idx;
        }
    }
    __syncthreads();

    const float nrm = sqrtf(((redW[0] + redW[1]) + (redW[2] + redW[3]))
                          + ((redW[4] + redW[5]) + (redW[6] + redW[7])) + 1e-8f);

    // ---- fp32 dot + distance: wave wv -> bgc = wv*4..+3, lane = j ----
    #pragma unroll
    for (int t = 0; t < 4; ++t) {
        const int bgc = wv * 4 + t;
        const int bg = bg0 + bgc;
        const int r = (lane + orienL[bgc]) & 63;
        float s = 0.f;
        #pragma unroll
        for (int h = 0; h < 4; ++h) {
            const float4* sp = (const float4*)&sat[(((size_t)bs * 4 + h) * 64 + r) * 16];
            const float4* gp = (const float4*)&grd[(((size_t)bg * 4 + h) * 64 + lane) * 16];
            #pragma unroll
            for (int c4 = 0; c4 < 4; ++c4) {
                float4 sv = sp[c4];
                float4 gv = gp[c4];
                s = fmaf(sv.x, gv.x, fmaf(sv.y, gv.y, fmaf(sv.z, gv.z, fmaf(sv.w, gv.w, s))));
            }
        }
        #pragma unroll
        for (int off = 32; off; off >>= 1) s += __shfl_xor(s, off);
        if (lane == 0)
            out[OUT_DIST + (size_t)bg * BS + bs] = 2.f - 2.f * (s / nrm);
    }
}

// ---------------- fallback (R3, verified): used only if ws too small ----------------
__device__ __forceinline__ int satIdxFB(int hw, int c4) {
    return hw * 16 + 4 * ((c4 + (hw >> 1)) & 3);
}
__device__ __forceinline__ float rot_add(int baddr, float p) {
    return __int_as_float(__builtin_amdgcn_ds_bpermute(baddr, __float_as_int(p)));
}
__device__ __forceinline__ float dot_rev(const float4 s0, const float4 s1,
                                         const float4 s2, const float4 s3,
                                         const float* __restrict__ g) {
    float p0 = fmaf(s0.x, g[15], fmaf(s0.y, g[14], fmaf(s0.z, g[13], s0.w * g[12])));
    float p1 = fmaf(s1.x, g[11], fmaf(s1.y, g[10], fmaf(s1.z, g[ 9], s1.w * g[ 8])));
    float p2 = fmaf(s2.x, g[ 7], fmaf(s2.y, g[ 6], fmaf(s2.z, g[ 5], s2.w * g[ 4])));
    float p3 = fmaf(s3.x, g[ 3], fmaf(s3.y, g[ 2], fmaf(s3.z, g[ 1], s3.w * g[ 0])));
    return (p0 + p1) + (p2 + p3);
}
#define NB 8
__global__ __launch_bounds__(256)
void pf_fused_fb(const float* __restrict__ sat, const float* __restrict__ grd,
                 float* __restrict__ out)
{
    __shared__ float satL[H * W * C];
    __shared__ float partL[NB * 4 * W];
    __shared__ float sumL[4];
    __shared__ float dotP[NB * 4];
    __shared__ int   orienL[NB];
    const int bs = blockIdx.y, bg0 = blockIdx.x * NB;
    const int tid = threadIdx.x, wv = tid >> 6, lane = tid & 63;
    const float4* sp = (const float4*)(sat + (((size_t)bs * H + wv) * W + lane) * C);
    const float4 s0 = sp[0], s1 = sp[1], s2 = sp[2], s3 = sp[3];
    { const int hw = wv * W + lane;
      *(float4*)&satL[satIdxFB(hw,0)] = s0; *(float4*)&satL[satIdxFB(hw,1)] = s1;
      *(float4*)&satL[satIdxFB(hw,2)] = s2; *(float4*)&satL[satIdxFB(hw,3)] = s3; }
    { float a = fmaf(s0.x,s0.x,fmaf(s0.y,s0.y,fmaf(s0.z,s0.z,s0.w*s0.w)));
      float b = fmaf(s1.x,s1.x,fmaf(s1.y,s1.y,fmaf(s1.z,s1.z,s1.w*s1.w)));
      float c = fmaf(s2.x,s2.x,fmaf(s2.y,s2.y,fmaf(s2.z,s2.z,s2.w*s2.w)));
      float d = fmaf(s3.x,s3.x,fmaf(s3.y,s3.y,fmaf(s3.z,s3.z,s3.w*s3.w)));
      float s = (a+b)+(c+d);
      #pragma unroll
      for (int off = 32; off; off >>= 1) s += __shfl_xor(s, off);
      if (lane == 0) sumL[wv] = s; }
    const float* gpB = grd + (size_t)(bg0 * H + wv) * W * C;
    #pragma unroll
    for (int bp = 0; bp < NB/2; ++bp) {
        const float* gA = gpB + (2*bp) * HWC;
        const float* gB2 = gpB + (2*bp+1) * HWC;
        float accA = 0.f, accB = 0.f;
        int baddr = lane << 2;
        #pragma unroll 2
        for (int j = 0; j < W; ++j) {
            float pA = dot_rev(s0,s1,s2,s3, gA + j*C);
            float pB = dot_rev(s0,s1,s2,s3, gB2 + j*C);
            accA += rot_add(baddr, pA); accB += rot_add(baddr, pB);
            baddr = (baddr + 4) & 255;
        }
        partL[((2*bp)*4 + wv)*W + lane] = accA;
        partL[((2*bp+1)*4 + wv)*W + lane] = accB;
    }
    __syncthreads();
    for (int b = wv; b < NB; b += 4) {
        float v = (partL[(b*4+0)*W+lane] + partL[(b*4+1)*W+lane])
                + (partL[(b*4+2)*W+lane] + partL[(b*4+3)*W+lane]);
        int idx = lane;
        #pragma unroll
        for (int off = 32; off; off >>= 1) {
            float ov = __shfl_xor(v, off); int oi = __shfl_xor(idx, off);
            if (ov > v || (ov == v && oi < idx)) { v = ov; idx = oi; }
        }
        if (lane == 0) { orienL[b] = idx; out[OUT_ORIEN + bs*BG + (bg0+b)] = (float)idx; }
    }
    __syncthreads();
    const float nrm = sqrtf(sumL[0]+sumL[1]+sumL[2]+sumL[3] + 1e-8f);
    { float dp[NB];
      #pragma unroll
      for (int b = 0; b < NB; ++b) {
          const int row = (lane + orienL[b]) & 63;
          const float* gRow = grd + (((size_t)(bg0+b)*H + wv)*W + lane)*C;
          float s = 0.f;
          #pragma unroll
          for (int c4 = 0; c4 < 4; ++c4) {
              float4 sv = *(const float4*)&satL[satIdxFB(wv*W+row, c4)];
              float4 gv = *(const float4*)(gRow + 4*c4);
              s = fmaf(sv.x,gv.x, fmaf(sv.y,gv.y, fmaf(sv.z,gv.z, fmaf(sv.w,gv.w, s))));
          }
          dp[b] = s;
      }
      #pragma unroll
      for (int b = 0; b < NB; ++b) {
          float s = dp[b];
          #pragma unroll
          for (int off = 32; off; off >>= 1) s += __shfl_xor(s, off);
          if (lane == 0) dotP[b*4 + wv] = s;
      } }
    __syncthreads();
    if (tid < NB) {
        float d = ((dotP[tid*4+0]+dotP[tid*4+1])+(dotP[tid*4+2]+dotP[tid*4+3])) / nrm;
        out[OUT_DIST + (size_t)(bg0+tid)*BS + bs] = 2.f - 2.f*d;
    }
}

extern "C" void kernel_launch(void* const* d_in, const int* in_sizes, int n_in,
                              void* d_out, int out_size, void* d_ws, size_t ws_size,
                              hipStream_t stream) {
    const float* sat = (const float*)d_in[0];
    const float* grd = (const float*)d_in[1];
    float* out = (float*)d_out;

    if (ws_size < WS_NEEDED) {
        hipMemcpyAsync(out,             sat, (size_t)SAT_ELEMS * sizeof(float),
                       hipMemcpyDeviceToDevice, stream);
        hipMemcpyAsync(out + SAT_ELEMS, grd, (size_t)SAT_ELEMS * sizeof(float),
                       hipMemcpyDeviceToDevice, stream);
        dim3 grid(BG / NB, BS);
        pf_fused_fb<<<grid, 256, 0, stream>>>(sat, grd, out);
        return;
    }

    unsigned short* Bpk = (unsigned short*)d_ws;
    pf_pack_b<<<96, 512, 0, stream>>>(sat, grd, Bpk, out);
    pf_fused<<<dim3(3, BS), 512, 0, stream>>>(sat, grd, Bpk, out);
}

// Round 11
// 49.653 us; speedup vs baseline: 1.4851x; 1.4351x over previous
//
#include <hip/hip_runtime.h>
#include <math.h>
#include <stdint.h>

// Problem: ProcessFeatures_83296595738632
// corr[bs,bg,i] = sum_{h,j,k} sat[bs,h,(i+j)%64,k] * grd[bg,h,j,15-k]
// orien = argmax_i corr (first-max); dot with cyclic shift orien, /||sat||
// distance[bg,bs] = 2-2*dot[bs,bg]; out: sat | grd | distance | orien(float)
//
// R11: TLP fix. Grid (6 x 96) = 576 blocks; block = 8 waves =
// (2 mtile-pairs) x (4-way K-split). Per wave: 2 mtiles, 32 steps of
// {4 ds_read A + 2 coalesced B loads + 8 MFMA(16x16x32)}. Cross-wave
// K-reduce in LDS. bf16x4 split numerics (R10-verified layouts).

#define BS   96
#define H    4
#define W    64
#define C    16
#define BG   96
#define HWC  (H*W*C)                  // 4096

#define SAT_ELEMS (BS*H*W*C)          // 393216
#define OUT_DIST  (2*SAT_ELEMS)       // 786432
#define OUT_ORIEN (OUT_DIST + BS*BG)  // 795648

#define WS_NEEDED ((size_t)2 * SAT_ELEMS * 2)   // 1.5 MB

typedef __attribute__((ext_vector_type(4)))  short short4v;
typedef __attribute__((ext_vector_type(8)))  short short8v;
typedef __attribute__((ext_vector_type(4)))  float f32x4;

__device__ __forceinline__ void bsplit(float x, unsigned short& hi, unsigned short& lo) {
    unsigned int u = __float_as_uint(x);
    unsigned int r = (u + 0x7FFFu + ((u >> 16) & 1u)) >> 16;   // RNE to bf16
    hi = (unsigned short)r;
    float hf = __uint_as_float(r << 16);
    float l = x - hf;
    unsigned int ul = __float_as_uint(l);
    unsigned int rl = (ul + 0x7FFFu + ((ul >> 16) & 1u)) >> 16;
    lo = (unsigned short)rl;
}

// ---------------- prologue: pack B fragments (16x16x32 layout) + passthrough ----
// Fragment (j,kh,nt6,pl): lane l, elem e ->
//   B[k = (l>>4)*8+e][col = l&15] = grdR[j][nt6*16 + (l&15)][kh*32 + (l>>4)*8 + e]
//   grdR[j][bg][hk] = grd[bg][hk>>4][j][15-(hk&15)]
__global__ __launch_bounds__(512)
void pf_pack_b(const float* __restrict__ sat, const float* __restrict__ grd,
               unsigned short* __restrict__ Bpk, float* __restrict__ out)
{
    int t = blockIdx.x * 512 + threadIdx.x;    // < 49152 = 64j * 2kh * 6nt * 64lane
    int lane = t & 63;
    int f    = t >> 6;            // fragment id: ((j*2+kh)*6 + nt6)
    int nt6  = f % 6;
    int g    = f / 6;
    int kh   = g & 1;
    int j    = g >> 1;

    int col = nt6 * 16 + (lane & 15);
    int u   = lane >> 4;
    int h   = kh * 2 + (u >> 1);
    int k0  = (u & 1) * 8;        // hk = kh*32 + u*8 -> within-h offset k0

    const float* row = grd + ((size_t)(col * 4 + h) * 64 + j) * 16 + (8 - k0);
    float tmp[8];
    *(float4*)&tmp[0] = *(const float4*)(row);
    *(float4*)&tmp[4] = *(const float4*)(row + 4);

    short8v hv, lv;
    #pragma unroll
    for (int e = 0; e < 8; ++e) {
        unsigned short hi, lo;
        bsplit(tmp[7 - e], hi, lo);          // value[e] = grd[...][15-k0-e]
        hv[e] = (short)hi; lv[e] = (short)lo;
    }
    size_t base = (size_t)f << 10;           // 1024 ushorts per fragment pair
    *(short8v*)&Bpk[base + lane * 8]       = hv;   // plane 0 (hi)
    *(short8v*)&Bpk[base + 512 + lane * 8] = lv;   // plane 1 (lo)

    // passthrough copies: out[0..] = sat, out[SAT..] = grd
    const float4* s4 = (const float4*)sat;
    const float4* g4 = (const float4*)grd;
    float4* o4 = (float4*)out;
    #pragma unroll
    for (int idx = t; idx < 2 * SAT_ELEMS / 4; idx += 49152) {
        o4[idx] = (idx < SAT_ELEMS / 4) ? s4[idx] : g4[idx - SAT_ELEMS / 4];
    }
}

// ---------------- fused: corr MFMA + argmax + dot + distance ----------------
#define MFMA16(a, b, c) __builtin_amdgcn_mfma_f32_16x16x32_bf16((a), (b), (c), 0, 0, 0)

__global__ __launch_bounds__(512, 4)
void pf_fused(const float* __restrict__ sat, const float* __restrict__ grd,
              const unsigned short* __restrict__ Bpk, float* __restrict__ out)
{
    __shared__ unsigned short sHi[4096], sLo[4096];   // satM planes, swizzled (16 KB)
    __shared__ float corrPart[4][64][17];             // 17.4 KB (odd stride)
    __shared__ float redW[8];
    __shared__ int   orienL[16];

    const int bs  = blockIdx.y;
    const int nt6 = blockIdx.x;          // 16-bg group
    const int bg0 = nt6 * 16;
    const int tid = threadIdx.x;
    const int wv  = tid >> 6, lane = tid & 63;
    const int u   = lane >> 4;
    const int mt2 = wv & 1;              // mtile pair: {2*mt2, 2*mt2+1}
    const int kq  = wv >> 1;             // K quarter: j in [kq*16, kq*16+16)

    // ---- stage satM (swizzled bf16 hi/lo) + norm partial ----
    // satM[w][hk] = sat[bs][hk>>4][w][hk&15]; chunk cc=hk>>3 at slot cc^(w&7)
    {
        const float4* satB = (const float4*)(sat + (size_t)bs * HWC);
        float np = 0.f;
        #pragma unroll
        for (int t = tid; t < 1024; t += 512) {
            float4 v = satB[t];
            int e = 4 * t;
            int h = e >> 10, w = (e >> 4) & 63, k = e & 15;
            int cc = (h * 16 + k) >> 3;
            int dst = w * 64 + ((cc ^ (w & 7)) * 8) + (k & 7);
            short4v hvv, lvv;
            unsigned short hi, lo;
            bsplit(v.x, hi, lo); hvv[0] = hi; lvv[0] = lo;
            bsplit(v.y, hi, lo); hvv[1] = hi; lvv[1] = lo;
            bsplit(v.z, hi, lo); hvv[2] = hi; lvv[2] = lo;
            bsplit(v.w, hi, lo); hvv[3] = hi; lvv[3] = lo;
            *(short4v*)&sHi[dst] = hvv;
            *(short4v*)&sLo[dst] = lvv;
            np = fmaf(v.x, v.x, fmaf(v.y, v.y, fmaf(v.z, v.z, fmaf(v.w, v.w, np))));
        }
        #pragma unroll
        for (int off = 32; off; off >>= 1) np += __shfl_xor(np, off);
        if (lane == 0) redW[wv] = np;
    }
    __syncthreads();

    // ---- corr GEMM: bf16x4, 2 mtiles per wave, K-slice 16 j (32 steps) ----
    f32x4 acc0 = {0.f, 0.f, 0.f, 0.f};     // mtile 2*mt2
    f32x4 acc1 = {0.f, 0.f, 0.f, 0.f};     // mtile 2*mt2+1
    const int m0 = mt2 * 2;
    const int mbase0 = m0 * 16 + (lane & 15);
    const int laneB = lane * 8;
    const unsigned short* __restrict__ bbase = Bpk + ((size_t)nt6 << 10) + laneB;

    #pragma unroll 4
    for (int jj = 0; jj < 16; ++jj) {
        const int j = kq * 16 + jj;
        const unsigned short* bj = bbase + ((size_t)(j * 12) << 10);
        #pragma unroll
        for (int kh = 0; kh < 2; ++kh) {
            // B fragment (shared by both mtiles)
            const unsigned short* bp = bj + ((size_t)(kh * 6) << 10);
            short8v bh = *(const short8v*)bp;
            short8v bl = *(const short8v*)(bp + 512);
            // mtile m0
            {
                const int r = (mbase0 + j) & 63;
                const int aoff = (r << 6) + ((((kh * 4 + u) ^ (r & 7))) << 3);
                short8v ah = *(const short8v*)&sHi[aoff];
                short8v al = *(const short8v*)&sLo[aoff];
                acc0 = MFMA16(ah, bh, acc0);
                acc0 = MFMA16(ah, bl, acc0);
                acc0 = MFMA16(al, bh, acc0);
                acc0 = MFMA16(al, bl, acc0);
            }
            // mtile m0+1 (rows +16)
            {
                const int r = (mbase0 + 16 + j) & 63;
                const int aoff = (r << 6) + ((((kh * 4 + u) ^ (r & 7))) << 3);
                short8v ah = *(const short8v*)&sHi[aoff];
                short8v al = *(const short8v*)&sLo[aoff];
                acc1 = MFMA16(ah, bh, acc1);
                acc1 = MFMA16(ah, bl, acc1);
                acc1 = MFMA16(al, bh, acc1);
                acc1 = MFMA16(al, bl, acc1);
            }
        }
    }

    // ---- C/D -> corrPart[kq]: col = lane&15, row = m*16 + (lane>>4)*4 + reg ----
    {
        const int gcol = lane & 15;
        const int rr0 = m0 * 16 + u * 4;
        #pragma unroll
        for (int reg = 0; reg < 4; ++reg) {
            corrPart[kq][rr0 + reg][gcol]      = acc0[reg];
            corrPart[kq][rr0 + 16 + reg][gcol] = acc1[reg];
        }
    }
    __syncthreads();

    // ---- argmax per bg (first-max tie-break): wave wv -> bgc = wv*2..+1 ----
    #pragma unroll
    for (int t = 0; t < 2; ++t) {
        const int bgc = wv * 2 + t;
        float v = (corrPart[0][lane][bgc] + corrPart[1][lane][bgc])
                + (corrPart[2][lane][bgc] + corrPart[3][lane][bgc]);
        int idx = lane;
        #pragma unroll
        for (int off = 32; off; off >>= 1) {
            float ov = __shfl_xor(v, off);
            int   oi = __shfl_xor(idx, off);
            if (ov > v || (ov == v && oi < idx)) { v = ov; idx = oi; }
        }
        if (lane == 0) {
            orienL[bgc] = idx;
            out[OUT_ORIEN + bs * BG + bg0 + bgc] = (float)idx;
        }
    }
    __syncthreads();

    const float nrm = sqrtf(((redW[0] + redW[1]) + (redW[2] + redW[3]))
                          + ((redW[4] + redW[5]) + (redW[6] + redW[7])) + 1e-8f);

    // ---- fp32 dot + distance: wave wv -> bgc = wv*2..+1, lane = j ----
    #pragma unroll
    for (int t = 0; t < 2; ++t) {
        const int bgc = wv * 2 + t;
        const int bg = bg0 + bgc;
        const int r = (lane + orienL[bgc]) & 63;
        float s = 0.f;
        #pragma unroll
        for (int h = 0; h < 4; ++h) {
            const float4* sp = (const float4*)&sat[(((size_t)bs * 4 + h) * 64 + r) * 16];
            const float4* gp = (const float4*)&grd[(((size_t)bg * 4 + h) * 64 + lane) * 16];
            #pragma unroll
            for (int c4 = 0; c4 < 4; ++c4) {
                float4 sv = sp[c4];
                float4 gv = gp[c4];
                s = fmaf(sv.x, gv.x, fmaf(sv.y, gv.y, fmaf(sv.z, gv.z, fmaf(sv.w, gv.w, s))));
            }
        }
        #pragma unroll
        for (int off = 32; off; off >>= 1) s += __shfl_xor(s, off);
        if (lane == 0)
            out[OUT_DIST + (size_t)bg * BS + bs] = 2.f - 2.f * (s / nrm);
    }
}

// ---------------- fallback (R3, verified): used only if ws too small ----------------
__device__ __forceinline__ int satIdxFB(int hw, int c4) {
    return hw * 16 + 4 * ((c4 + (hw >> 1)) & 3);
}
__device__ __forceinline__ float rot_add(int baddr, float p) {
    return __int_as_float(__builtin_amdgcn_ds_bpermute(baddr, __float_as_int(p)));
}
__device__ __forceinline__ float dot_rev(const float4 s0, const float4 s1,
                                         const float4 s2, const float4 s3,
                                         const float* __restrict__ g) {
    float p0 = fmaf(s0.x, g[15], fmaf(s0.y, g[14], fmaf(s0.z, g[13], s0.w * g[12])));
    float p1 = fmaf(s1.x, g[11], fmaf(s1.y, g[10], fmaf(s1.z, g[ 9], s1.w * g[ 8])));
    float p2 = fmaf(s2.x, g[ 7], fmaf(s2.y, g[ 6], fmaf(s2.z, g[ 5], s2.w * g[ 4])));
    float p3 = fmaf(s3.x, g[ 3], fmaf(s3.y, g[ 2], fmaf(s3.z, g[ 1], s3.w * g[ 0])));
    return (p0 + p1) + (p2 + p3);
}
#define NB 8
__global__ __launch_bounds__(256)
void pf_fused_fb(const float* __restrict__ sat, const float* __restrict__ grd,
                 float* __restrict__ out)
{
    __shared__ float satL[H * W * C];
    __shared__ float partL[NB * 4 * W];
    __shared__ float sumL[4];
    __shared__ float dotP[NB * 4];
    __shared__ int   orienL[NB];
    const int bs = blockIdx.y, bg0 = blockIdx.x * NB;
    const int tid = threadIdx.x, wv = tid >> 6, lane = tid & 63;
    const float4* sp = (const float4*)(sat + (((size_t)bs * H + wv) * W + lane) * C);
    const float4 s0 = sp[0], s1 = sp[1], s2 = sp[2], s3 = sp[3];
    { const int hw = wv * W + lane;
      *(float4*)&satL[satIdxFB(hw,0)] = s0; *(float4*)&satL[satIdxFB(hw,1)] = s1;
      *(float4*)&satL[satIdxFB(hw,2)] = s2; *(float4*)&satL[satIdxFB(hw,3)] = s3; }
    { float a = fmaf(s0.x,s0.x,fmaf(s0.y,s0.y,fmaf(s0.z,s0.z,s0.w*s0.w)));
      float b = fmaf(s1.x,s1.x,fmaf(s1.y,s1.y,fmaf(s1.z,s1.z,s1.w*s1.w)));
      float c = fmaf(s2.x,s2.x,fmaf(s2.y,s2.y,fmaf(s2.z,s2.z,s2.w*s2.w)));
      float d = fmaf(s3.x,s3.x,fmaf(s3.y,s3.y,fmaf(s3.z,s3.z,s3.w*s3.w)));
      float s = (a+b)+(c+d);
      #pragma unroll
      for (int off = 32; off; off >>= 1) s += __shfl_xor(s, off);
      if (lane == 0) sumL[wv] = s; }
    const float* gpB = grd + (size_t)(bg0 * H + wv) * W * C;
    #pragma unroll
    for (int bp = 0; bp < NB/2; ++bp) {
        const float* gA = gpB + (2*bp) * HWC;
        const float* gB2 = gpB + (2*bp+1) * HWC;
        float accA = 0.f, accB = 0.f;
        int baddr = lane << 2;
        #pragma unroll 2
        for (int j = 0; j < W; ++j) {
            float pA = dot_rev(s0,s1,s2,s3, gA + j*C);
            float pB = dot_rev(s0,s1,s2,s3, gB2 + j*C);
            accA += rot_add(baddr, pA); accB += rot_add(baddr, pB);
            baddr = (baddr + 4) & 255;
        }
        partL[((2*bp)*4 + wv)*W + lane] = accA;
        partL[((2*bp+1)*4 + wv)*W + lane] = accB;
    }
    __syncthreads();
    for (int b = wv; b < NB; b += 4) {
        float v = (partL[(b*4+0)*W+lane] + partL[(b*4+1)*W+lane])
                + (partL[(b*4+2)*W+lane] + partL[(b*4+3)*W+lane]);
        int idx = lane;
        #pragma unroll
        for (int off = 32; off; off >>= 1) {
            float ov = __shfl_xor(v, off); int oi = __shfl_xor(idx, off);
            if (ov > v || (ov == v && oi < idx)) { v = ov; idx = oi; }
        }
        if (lane == 0) { orienL[b] = idx; out[OUT_ORIEN + bs*BG + (bg0+b)] = (float)idx; }
    }
    __syncthreads();
    const float nrm = sqrtf(sumL[0]+sumL[1]+sumL[2]+sumL[3] + 1e-8f);
    { float dp[NB];
      #pragma unroll
      for (int b = 0; b < NB; ++b) {
          const int row = (lane + orienL[b]) & 63;
          const float* gRow = grd + (((size_t)(bg0+b)*H + wv)*W + lane)*C;
          float s = 0.f;
          #pragma unroll
          for (int c4 = 0; c4 < 4; ++c4) {
              float4 sv = *(const float4*)&satL[satIdxFB(wv*W+row, c4)];
              float4 gv = *(const float4*)(gRow + 4*c4);
              s = fmaf(sv.x,gv.x, fmaf(sv.y,gv.y, fmaf(sv.z,gv.z, fmaf(sv.w,gv.w, s))));
          }
          dp[b] = s;
      }
      #pragma unroll
      for (int b = 0; b < NB; ++b) {
          float s = dp[b];
          #pragma unroll
          for (int off = 32; off; off >>= 1) s += __shfl_xor(s, off);
          if (lane == 0) dotP[b*4 + wv] = s;
      } }
    __syncthreads();
    if (tid < NB) {
        float d = ((dotP[tid*4+0]+dotP[tid*4+1])+(dotP[tid*4+2]+dotP[tid*4+3])) / nrm;
        out[OUT_DIST + (size_t)(bg0+tid)*BS + bs] = 2.f - 2.f*d;
    }
}

extern "C" void kernel_launch(void* const* d_in, const int* in_sizes, int n_in,
                              void* d_out, int out_size, void* d_ws, size_t ws_size,
                              hipStream_t stream) {
    const float* sat = (const float*)d_in[0];
    const float* grd = (const float*)d_in[1];
    float* out = (float*)d_out;

    if (ws_size < WS_NEEDED) {
        hipMemcpyAsync(out,             sat, (size_t)SAT_ELEMS * sizeof(float),
                       hipMemcpyDeviceToDevice, stream);
        hipMemcpyAsync(out + SAT_ELEMS, grd, (size_t)SAT_ELEMS * sizeof(float),
                       hipMemcpyDeviceToDevice, stream);
        dim3 grid(BG / NB, BS);
        pf_fused_fb<<<grid, 256, 0, stream>>>(sat, grd, out);
        return;
    }

    unsigned short* Bpk = (unsigned short*)d_ws;
    pf_pack_b<<<96, 512, 0, stream>>>(sat, grd, Bpk, out);
    pf_fused<<<dim3(6, BS), 512, 0, stream>>>(sat, grd, Bpk, out);
}

// Round 12
// 48.993 us; speedup vs baseline: 1.5052x; 1.0135x over previous
//
#include <hip/hip_runtime.h>
#include <math.h>
#include <stdint.h>

// Problem: ProcessFeatures_83296595738632
// corr[bs,bg,i] = sum_{h,j,k} sat[bs,h,(i+j)%64,k] * grd[bg,h,j,15-k]
// orien = argmax_i corr (first-max); dot with cyclic shift orien, /||sat||
// distance[bg,bs] = 2-2*dot[bs,bg]; out: sat | grd | distance | orien(float)
//
// R12: 8-way K-split, 4 mtiles per wave (B reuse x2, VMEM halved), full-unroll
// strength-reduced addressing, next-step B prefetch in named regs, bf16x4
// numerics (R10/R11-verified fragment layouts).

#define BS   96
#define H    4
#define W    64
#define C    16
#define BG   96
#define HWC  (H*W*C)                  // 4096

#define SAT_ELEMS (BS*H*W*C)          // 393216
#define OUT_DIST  (2*SAT_ELEMS)       // 786432
#define OUT_ORIEN (OUT_DIST + BS*BG)  // 795648

#define WS_NEEDED ((size_t)2 * SAT_ELEMS * 2)   // 1.5 MB

typedef __attribute__((ext_vector_type(4)))  short short4v;
typedef __attribute__((ext_vector_type(8)))  short short8v;
typedef __attribute__((ext_vector_type(4)))  float f32x4;

__device__ __forceinline__ void bsplit(float x, unsigned short& hi, unsigned short& lo) {
    unsigned int u = __float_as_uint(x);
    unsigned int r = (u + 0x7FFFu + ((u >> 16) & 1u)) >> 16;   // RNE to bf16
    hi = (unsigned short)r;
    float hf = __uint_as_float(r << 16);
    float l = x - hf;
    unsigned int ul = __float_as_uint(l);
    unsigned int rl = (ul + 0x7FFFu + ((ul >> 16) & 1u)) >> 16;
    lo = (unsigned short)rl;
}

// ---------------- prologue: pack B fragments (16x16x32 layout) + passthrough ----
// Fragment (j,kh,nt6,pl): lane l, elem e ->
//   B[k = (l>>4)*8+e][col = l&15] = grdR[j][nt6*16 + (l&15)][kh*32 + (l>>4)*8 + e]
//   grdR[j][bg][hk] = grd[bg][hk>>4][j][15-(hk&15)]
__global__ __launch_bounds__(512)
void pf_pack_b(const float* __restrict__ sat, const float* __restrict__ grd,
               unsigned short* __restrict__ Bpk, float* __restrict__ out)
{
    int t = blockIdx.x * 512 + threadIdx.x;    // < 49152 = 64j * 2kh * 6nt * 64lane
    int lane = t & 63;
    int f    = t >> 6;            // fragment id: ((j*2+kh)*6 + nt6)
    int nt6  = f % 6;
    int g    = f / 6;
    int kh   = g & 1;
    int j    = g >> 1;

    int col = nt6 * 16 + (lane & 15);
    int u   = lane >> 4;
    int h   = kh * 2 + (u >> 1);
    int k0  = (u & 1) * 8;        // hk = kh*32 + u*8 -> within-h offset k0

    const float* row = grd + ((size_t)(col * 4 + h) * 64 + j) * 16 + (8 - k0);
    float tmp[8];
    *(float4*)&tmp[0] = *(const float4*)(row);
    *(float4*)&tmp[4] = *(const float4*)(row + 4);

    short8v hv, lv;
    #pragma unroll
    for (int e = 0; e < 8; ++e) {
        unsigned short hi, lo;
        bsplit(tmp[7 - e], hi, lo);          // value[e] = grd[...][15-k0-e]
        hv[e] = (short)hi; lv[e] = (short)lo;
    }
    size_t base = (size_t)f << 10;           // 1024 ushorts per fragment pair
    *(short8v*)&Bpk[base + lane * 8]       = hv;   // plane 0 (hi)
    *(short8v*)&Bpk[base + 512 + lane * 8] = lv;   // plane 1 (lo)

    // passthrough copies: out[0..] = sat, out[SAT..] = grd
    const float4* s4 = (const float4*)sat;
    const float4* g4 = (const float4*)grd;
    float4* o4 = (float4*)out;
    #pragma unroll
    for (int idx = t; idx < 2 * SAT_ELEMS / 4; idx += 49152) {
        o4[idx] = (idx < SAT_ELEMS / 4) ? s4[idx] : g4[idx - SAT_ELEMS / 4];
    }
}

// ---------------- fused: corr MFMA + argmax + dot + distance ----------------
#define MFMA16(a, b, c) __builtin_amdgcn_mfma_f32_16x16x32_bf16((a), (b), (c), 0, 0, 0)

__global__ __launch_bounds__(512, 4)
void pf_fused(const float* __restrict__ sat, const float* __restrict__ grd,
              const unsigned short* __restrict__ Bpk, float* __restrict__ out)
{
    __shared__ unsigned short sHi[4096], sLo[4096];   // satM planes, swizzled (16 KB)
    __shared__ float corrPart[8][64][17];             // 34.8 KB (odd stride)
    __shared__ float redW[8];
    __shared__ int   orienL[16];

    const int bs  = blockIdx.y;
    const int nt6 = blockIdx.x;          // 16-bg group
    const int bg0 = nt6 * 16;
    const int tid = threadIdx.x;
    const int wv  = tid >> 6, lane = tid & 63;
    const int u   = lane >> 4;
    const int kq  = wv;                  // K eighth: j in [kq*8, kq*8+8)

    // ---- stage satM (swizzled bf16 hi/lo) + norm partial ----
    // satM[w][hk] = sat[bs][hk>>4][w][hk&15]; chunk cc=hk>>3 at slot cc^(w&7)
    {
        const float4* satB = (const float4*)(sat + (size_t)bs * HWC);
        float np = 0.f;
        #pragma unroll
        for (int t = tid; t < 1024; t += 512) {
            float4 v = satB[t];
            int e = 4 * t;
            int h = e >> 10, w = (e >> 4) & 63, k = e & 15;
            int cc = (h * 16 + k) >> 3;
            int dst = w * 64 + ((cc ^ (w & 7)) * 8) + (k & 7);
            short4v hvv, lvv;
            unsigned short hi, lo;
            bsplit(v.x, hi, lo); hvv[0] = hi; lvv[0] = lo;
            bsplit(v.y, hi, lo); hvv[1] = hi; lvv[1] = lo;
            bsplit(v.z, hi, lo); hvv[2] = hi; lvv[2] = lo;
            bsplit(v.w, hi, lo); hvv[3] = hi; lvv[3] = lo;
            *(short4v*)&sHi[dst] = hvv;
            *(short4v*)&sLo[dst] = lvv;
            np = fmaf(v.x, v.x, fmaf(v.y, v.y, fmaf(v.z, v.z, fmaf(v.w, v.w, np))));
        }
        #pragma unroll
        for (int off = 32; off; off >>= 1) np += __shfl_xor(np, off);
        if (lane == 0) redW[wv] = np;
    }
    __syncthreads();

    // ---- corr GEMM: bf16x4, 4 mtiles per wave, K-slice 8 j ----
    f32x4 acc0 = {0.f,0.f,0.f,0.f}, acc1 = {0.f,0.f,0.f,0.f};
    f32x4 acc2 = {0.f,0.f,0.f,0.f}, acc3 = {0.f,0.f,0.f,0.f};

    const int l15 = lane & 15;
    // B fragment base for this wave: fragment id f = (j*2+kh)*6 + nt6
    const unsigned short* __restrict__ bb =
        Bpk + (((size_t)(kq * 8 * 2) * 6 + nt6) << 10) + lane * 8;
    // ushort strides: per kh = 6<<10, per j = 12<<10

    // preload jj=0 B fragments (both kh)
    short8v bh0 = *(const short8v*)(bb);
    short8v bl0 = *(const short8v*)(bb + 512);
    short8v bh1 = *(const short8v*)(bb + (6 << 10));
    short8v bl1 = *(const short8v*)(bb + (6 << 10) + 512);

    #define MT_STEP(ACC, mnum, J, BH0, BL0, BH1, BL1) { \
        const int r_ = ((mnum) * 16 + l15 + (J)) & 63; \
        const int base_ = r_ << 6; \
        const int rs_ = r_ & 7; \
        { const int aoff_ = base_ + (((u) ^ rs_) << 3); \
          short8v ah_ = *(const short8v*)&sHi[aoff_]; \
          short8v al_ = *(const short8v*)&sLo[aoff_]; \
          ACC = MFMA16(ah_, BH0, ACC); ACC = MFMA16(ah_, BL0, ACC); \
          ACC = MFMA16(al_, BH0, ACC); ACC = MFMA16(al_, BL0, ACC); } \
        { const int aoff_ = base_ + ((((4 + u)) ^ rs_) << 3); \
          short8v ah_ = *(const short8v*)&sHi[aoff_]; \
          short8v al_ = *(const short8v*)&sLo[aoff_]; \
          ACC = MFMA16(ah_, BH1, ACC); ACC = MFMA16(ah_, BL1, ACC); \
          ACC = MFMA16(al_, BH1, ACC); ACC = MFMA16(al_, BL1, ACC); } }

    #pragma unroll
    for (int jj = 0; jj < 8; ++jj) {
        const int j = kq * 8 + jj;
        // prefetch next jj's B fragments (4 coalesced 16B loads in flight)
        short8v nh0, nl0, nh1, nl1;
        if (jj < 7) {
            const unsigned short* nb = bb + (size_t)(jj + 1) * (12 << 10);
            nh0 = *(const short8v*)(nb);
            nl0 = *(const short8v*)(nb + 512);
            nh1 = *(const short8v*)(nb + (6 << 10));
            nl1 = *(const short8v*)(nb + (6 << 10) + 512);
        }
        MT_STEP(acc0, 0, j, bh0, bl0, bh1, bl1);
        MT_STEP(acc1, 1, j, bh0, bl0, bh1, bl1);
        MT_STEP(acc2, 2, j, bh0, bl0, bh1, bl1);
        MT_STEP(acc3, 3, j, bh0, bl0, bh1, bl1);
        if (jj < 7) { bh0 = nh0; bl0 = nl0; bh1 = nh1; bl1 = nl1; }
    }
    #undef MT_STEP

    // ---- C/D -> corrPart[kq]: col = lane&15, row = m*16 + (lane>>4)*4 + reg ----
    {
        const int rr = u * 4;
        #pragma unroll
        for (int reg = 0; reg < 4; ++reg) {
            corrPart[kq][rr + reg][l15]      = acc0[reg];
            corrPart[kq][16 + rr + reg][l15] = acc1[reg];
            corrPart[kq][32 + rr + reg][l15] = acc2[reg];
            corrPart[kq][48 + rr + reg][l15] = acc3[reg];
        }
    }
    __syncthreads();

    // ---- argmax per bg (first-max tie-break): wave wv -> bgc = wv*2..+1 ----
    #pragma unroll
    for (int t = 0; t < 2; ++t) {
        const int bgc = wv * 2 + t;
        float v = ((corrPart[0][lane][bgc] + corrPart[1][lane][bgc])
                +  (corrPart[2][lane][bgc] + corrPart[3][lane][bgc]))
                + ((corrPart[4][lane][bgc] + corrPart[5][lane][bgc])
                +  (corrPart[6][lane][bgc] + corrPart[7][lane][bgc]));
        int idx = lane;
        #pragma unroll
        for (int off = 32; off; off >>= 1) {
            float ov = __shfl_xor(v, off);
            int   oi = __shfl_xor(idx, off);
            if (ov > v || (ov == v && oi < idx)) { v = ov; idx = oi; }
        }
        if (lane == 0) {
            orienL[bgc] = idx;
            out[OUT_ORIEN + bs * BG + bg0 + bgc] = (float)idx;
        }
    }
    __syncthreads();

    const float nrm = sqrtf(((redW[0] + redW[1]) + (redW[2] + redW[3]))
                          + ((redW[4] + redW[5]) + (redW[6] + redW[7])) + 1e-8f);

    // ---- fp32 dot + distance: wave wv -> bgc = wv*2..+1, lane = j ----
    #pragma unroll
    for (int t = 0; t < 2; ++t) {
        const int bgc = wv * 2 + t;
        const int bg = bg0 + bgc;
        const int r = (lane + orienL[bgc]) & 63;
        float s = 0.f;
        #pragma unroll
        for (int h = 0; h < 4; ++h) {
            const float4* sp = (const float4*)&sat[(((size_t)bs * 4 + h) * 64 + r) * 16];
            const float4* gp = (const float4*)&grd[(((size_t)bg * 4 + h) * 64 + lane) * 16];
            #pragma unroll
            for (int c4 = 0; c4 < 4; ++c4) {
                float4 sv = sp[c4];
                float4 gv = gp[c4];
                s = fmaf(sv.x, gv.x, fmaf(sv.y, gv.y, fmaf(sv.z, gv.z, fmaf(sv.w, gv.w, s))));
            }
        }
        #pragma unroll
        for (int off = 32; off; off >>= 1) s += __shfl_xor(s, off);
        if (lane == 0)
            out[OUT_DIST + (size_t)bg * BS + bs] = 2.f - 2.f * (s / nrm);
    }
}

// ---------------- fallback (R3, verified): used only if ws too small ----------------
__device__ __forceinline__ int satIdxFB(int hw, int c4) {
    return hw * 16 + 4 * ((c4 + (hw >> 1)) & 3);
}
__device__ __forceinline__ float rot_add(int baddr, float p) {
    return __int_as_float(__builtin_amdgcn_ds_bpermute(baddr, __float_as_int(p)));
}
__device__ __forceinline__ float dot_rev(const float4 s0, const float4 s1,
                                         const float4 s2, const float4 s3,
                                         const float* __restrict__ g) {
    float p0 = fmaf(s0.x, g[15], fmaf(s0.y, g[14], fmaf(s0.z, g[13], s0.w * g[12])));
    float p1 = fmaf(s1.x, g[11], fmaf(s1.y, g[10], fmaf(s1.z, g[ 9], s1.w * g[ 8])));
    float p2 = fmaf(s2.x, g[ 7], fmaf(s2.y, g[ 6], fmaf(s2.z, g[ 5], s2.w * g[ 4])));
    float p3 = fmaf(s3.x, g[ 3], fmaf(s3.y, g[ 2], fmaf(s3.z, g[ 1], s3.w * g[ 0])));
    return (p0 + p1) + (p2 + p3);
}
#define NB 8
__global__ __launch_bounds__(256)
void pf_fused_fb(const float* __restrict__ sat, const float* __restrict__ grd,
                 float* __restrict__ out)
{
    __shared__ float satL[H * W * C];
    __shared__ float partL[NB * 4 * W];
    __shared__ float sumL[4];
    __shared__ float dotP[NB * 4];
    __shared__ int   orienL[NB];
    const int bs = blockIdx.y, bg0 = blockIdx.x * NB;
    const int tid = threadIdx.x, wv = tid >> 6, lane = tid & 63;
    const float4* sp = (const float4*)(sat + (((size_t)bs * H + wv) * W + lane) * C);
    const float4 s0 = sp[0], s1 = sp[1], s2 = sp[2], s3 = sp[3];
    { const int hw = wv * W + lane;
      *(float4*)&satL[satIdxFB(hw,0)] = s0; *(float4*)&satL[satIdxFB(hw,1)] = s1;
      *(float4*)&satL[satIdxFB(hw,2)] = s2; *(float4*)&satL[satIdxFB(hw,3)] = s3; }
    { float a = fmaf(s0.x,s0.x,fmaf(s0.y,s0.y,fmaf(s0.z,s0.z,s0.w*s0.w)));
      float b = fmaf(s1.x,s1.x,fmaf(s1.y,s1.y,fmaf(s1.z,s1.z,s1.w*s1.w)));
      float c = fmaf(s2.x,s2.x,fmaf(s2.y,s2.y,fmaf(s2.z,s2.z,s2.w*s2.w)));
      float d = fmaf(s3.x,s3.x,fmaf(s3.y,s3.y,fmaf(s3.z,s3.z,s3.w*s3.w)));
      float s = (a+b)+(c+d);
      #pragma unroll
      for (int off = 32; off; off >>= 1) s += __shfl_xor(s, off);
      if (lane == 0) sumL[wv] = s; }
    const float* gpB = grd + (size_t)(bg0 * H + wv) * W * C;
    #pragma unroll
    for (int bp = 0; bp < NB/2; ++bp) {
        const float* gA = gpB + (2*bp) * HWC;
        const float* gB2 = gpB + (2*bp+1) * HWC;
        float accA = 0.f, accB = 0.f;
        int baddr = lane << 2;
        #pragma unroll 2
        for (int j = 0; j < W; ++j) {
            float pA = dot_rev(s0,s1,s2,s3, gA + j*C);
            float pB = dot_rev(s0,s1,s2,s3, gB2 + j*C);
            accA += rot_add(baddr, pA); accB += rot_add(baddr, pB);
            baddr = (baddr + 4) & 255;
        }
        partL[((2*bp)*4 + wv)*W + lane] = accA;
        partL[((2*bp+1)*4 + wv)*W + lane] = accB;
    }
    __syncthreads();
    for (int b = wv; b < NB; b += 4) {
        float v = (partL[(b*4+0)*W+lane] + partL[(b*4+1)*W+lane])
                + (partL[(b*4+2)*W+lane] + partL[(b*4+3)*W+lane]);
        int idx = lane;
        #pragma unroll
        for (int off = 32; off; off >>= 1) {
            float ov = __shfl_xor(v, off); int oi = __shfl_xor(idx, off);
            if (ov > v || (ov == v && oi < idx)) { v = ov; idx = oi; }
        }
        if (lane == 0) { orienL[b] = idx; out[OUT_ORIEN + bs*BG + (bg0+b)] = (float)idx; }
    }
    __syncthreads();
    const float nrm = sqrtf(sumL[0]+sumL[1]+sumL[2]+sumL[3] + 1e-8f);
    { float dp[NB];
      #pragma unroll
      for (int b = 0; b < NB; ++b) {
          const int row = (lane + orienL[b]) & 63;
          const float* gRow = grd + (((size_t)(bg0+b)*H + wv)*W + lane)*C;
          float s = 0.f;
          #pragma unroll
          for (int c4 = 0; c4 < 4; ++c4) {
              float4 sv = *(const float4*)&satL[satIdxFB(wv*W+row, c4)];
              float4 gv = *(const float4*)(gRow + 4*c4);
              s = fmaf(sv.x,gv.x, fmaf(sv.y,gv.y, fmaf(sv.z,gv.z, fmaf(sv.w,gv.w, s))));
          }
          dp[b] = s;
      }
      #pragma unroll
      for (int b = 0; b < NB; ++b) {
          float s = dp[b];
          #pragma unroll
          for (int off = 32; off; off >>= 1) s += __shfl_xor(s, off);
          if (lane == 0) dotP[b*4 + wv] = s;
      } }
    __syncthreads();
    if (tid < NB) {
        float d = ((dotP[tid*4+0]+dotP[tid*4+1])+(dotP[tid*4+2]+dotP[tid*4+3])) / nrm;
        out[OUT_DIST + (size_t)(bg0+tid)*BS + bs] = 2.f - 2.f*d;
    }
}

extern "C" void kernel_launch(void* const* d_in, const int* in_sizes, int n_in,
                              void* d_out, int out_size, void* d_ws, size_t ws_size,
                              hipStream_t stream) {
    const float* sat = (const float*)d_in[0];
    const float* grd = (const float*)d_in[1];
    float* out = (float*)d_out;

    if (ws_size < WS_NEEDED) {
        hipMemcpyAsync(out,             sat, (size_t)SAT_ELEMS * sizeof(float),
                       hipMemcpyDeviceToDevice, stream);
        hipMemcpyAsync(out + SAT_ELEMS, grd, (size_t)SAT_ELEMS * sizeof(float),
                       hipMemcpyDeviceToDevice, stream);
        dim3 grid(BG / NB, BS);
        pf_fused_fb<<<grid, 256, 0, stream>>>(sat, grd, out);
        return;
    }

    unsigned short* Bpk = (unsigned short*)d_ws;
    pf_pack_b<<<96, 512, 0, stream>>>(sat, grd, Bpk, out);
    pf_fused<<<dim3(6, BS), 512, 0, stream>>>(sat, grd, Bpk, out);
}